// Round 10
// baseline (178.845 us; speedup 1.0000x reference)
//
#include <hip/hip_runtime.h>
#include <hip/hip_bf16.h>

// ---------------------------------------------------------------------------
// GraphAttentionLayer: scores = (x*w_map) @ x^T ; attn = softmax(scores);
// agg = attn @ x ; out = agg@w_att^T + x@w_res^T ; BN(train) ; SELU.
// B=8, N=2048, D=256. All-bf16 MFMA pipeline. No-max softmax (|s| <~ 4).
// R10: R9 fusion kept, epilogue made latency-clean:
//  - PV operand swap (A=Vt,B=P): C cols = query -> Agg stored with b64 writes,
//    linear computed as out^T (A=WC regs, B=Agg/Xs LDS) -> b128 B-reads and
//    float4 out stores.
//  - x rows DMA'd into dead buf-0 LDS at jt==31 (hidden); WC prefetched into
//    VGPRs right after the first epilogue barrier (hidden under combine).
//  - g1 partials parked f32 in dead Vt buf-0 (2 rounds of 128 d, q-swizzled).
//  - __launch_bounds__(512,1): LDS caps at 1 block/CU anyway; frees VGPRs.
// R8 lesson: no grid-wide spin sync. R5 lesson: no VGPR global loads while
// DMA in flight (WC prefetch issued only after the DMA-draining barrier).
// ---------------------------------------------------------------------------

typedef __attribute__((ext_vector_type(8))) short  bf16x8;   // 8 bf16 = 4 VGPRs
typedef __attribute__((ext_vector_type(4))) float  f32x4;

#define MFMA16(a, b, c) __builtin_amdgcn_mfma_f32_16x16x32_bf16((a), (b), (c), 0, 0, 0)

constexpr int   NB = 8, NN = 2048, ND = 256;
constexpr int   ROWS = NB * NN;                 // 16384
constexpr float BN_EPS = 1e-5f;
constexpr float SELU_ALPHA = 1.6732632423543772f;
constexpr float SELU_SCALE = 1.0507009873554805f;

__device__ __forceinline__ unsigned short f2bf(float f) {
  union { float f; unsigned int u; } v; v.f = f;
  unsigned int u = v.u;
  u += 0x7FFFu + ((u >> 16) & 1u);              // round-to-nearest-even
  return (unsigned short)(u >> 16);
}
__device__ __forceinline__ float bf2f(unsigned short h) {
  union { float f; unsigned int u; } v; v.u = ((unsigned int)h) << 16;
  return v.f;
}

// async 16B/lane global->LDS; LDS dest is wave-uniform base + lane*16.
__device__ __forceinline__ void async_copy16(const unsigned short* g, unsigned short* l) {
  __builtin_amdgcn_global_load_lds(
      (const __attribute__((address_space(1))) void*)g,
      (__attribute__((address_space(3))) void*)l, 16, 0, 0);
}

// ---------------------------------------------------------------------------
// k0: blocks 0..511: x (fp32) -> bf16 into Xr (row-major) AND Xt (d-major),
//     32 rows per block. blocks 512..575: WC concat; block 512 zeroes sums.
// ---------------------------------------------------------------------------
__global__ __launch_bounds__(256) void k0_prep(const float* __restrict__ x,
                                               const float* __restrict__ w_att,
                                               const float* __restrict__ w_res,
                                               unsigned short* __restrict__ Xr,
                                               unsigned short* __restrict__ Xt,
                                               unsigned short* __restrict__ WC,
                                               float* __restrict__ sums) {
  __shared__ unsigned short Ls[32 * 264];
  const int t = threadIdx.x;
  if (blockIdx.x >= 512) {                      // ---- weight-concat path ----
    const int bid = blockIdx.x - 512;
    if (bid == 0 && t < 128)
      ((float4*)sums)[t] = make_float4(0.f, 0.f, 0.f, 0.f);   // 512 floats
    int f = (bid * 256 + t) * 8;                // < 131072
    int c = f >> 9, k = f & 511;
    const float* src = (k < 256) ? (w_att + c * 256 + k) : (w_res + c * 256 + (k - 256));
    float4 a = *(const float4*)src;
    float4 b = *(const float4*)(src + 4);
    union { unsigned short s[8]; uint4 v; } o;
    o.s[0] = f2bf(a.x); o.s[1] = f2bf(a.y); o.s[2] = f2bf(a.z); o.s[3] = f2bf(a.w);
    o.s[4] = f2bf(b.x); o.s[5] = f2bf(b.y); o.s[6] = f2bf(b.z); o.s[7] = f2bf(b.w);
    *(uint4*)(WC + f) = o.v;
    return;
  }
  const int b = blockIdx.x & 7, rt = blockIdx.x >> 3;    // rt < 64
  const int grb = b * NN + rt * 32;             // global row base
  const int c = (t & 31) * 8, r0 = t >> 5;
#pragma unroll
  for (int q = 0; q < 4; ++q) {
    int r = r0 + q * 8;                         // 32 rows
    const float* xp = x + (size_t)(grb + r) * 256 + c;
    float4 a = *(const float4*)xp;
    float4 d = *(const float4*)(xp + 4);
    union { unsigned short s[8]; uint4 v; } xb;
    xb.s[0] = f2bf(a.x); xb.s[1] = f2bf(a.y); xb.s[2] = f2bf(a.z); xb.s[3] = f2bf(a.w);
    xb.s[4] = f2bf(d.x); xb.s[5] = f2bf(d.y); xb.s[6] = f2bf(d.z); xb.s[7] = f2bf(d.w);
    *(uint4*)(Xr + (size_t)(grb + r) * 256 + c) = xb.v;
    *(uint4*)&Ls[r * 264 + c] = xb.v;
  }
  __syncthreads();
  unsigned short* dst = Xt + ((size_t)b * 256 + t) * 2048 + rt * 32;
#pragma unroll
  for (int k = 0; k < 4; ++k) {
    union { unsigned short s[8]; uint4 v; } o;
#pragma unroll
    for (int j = 0; j < 8; ++j) o.s[j] = Ls[(k * 8 + j) * 264 + t];
    *(uint4*)(dst + k * 8) = o.v;
  }
}

// ---------------------------------------------------------------------------
// k1: flash attention + fused linear. Block = (batch b, 64 rows), grid 256,
// 512 threads; 2 wave-groups split the j-range (R6 loop, frozen except the
// PV operand swap). Epilogue per header comment.
// ---------------------------------------------------------------------------
__global__ __launch_bounds__(512, 1) void k1_attn(const float* __restrict__ w_map,
                                                  const unsigned short* __restrict__ Xr,
                                                  const unsigned short* __restrict__ Xt,
                                                  const unsigned short* __restrict__ WC,
                                                  float* __restrict__ out,
                                                  float* __restrict__ sums) {
  __shared__ unsigned short Ks2[2][2][32 * 256];  // [buf][group]; buf0 = Xs later
  __shared__ unsigned short Vt2[2][2][256 * 32];  // [buf][group]; buf0 = OB later
  __shared__ unsigned short Psw[8][16 * 40];      // per-wave P scratch
  __shared__ float LbG[2][64];

  const int t = threadIdx.x;
  const int w = t >> 6, lane = t & 63, l15 = lane & 15, quad = lane >> 4;
  const int g = w >> 2, wg = w & 3;
  const int b = blockIdx.x & 7, it = blockIdx.x >> 3;
  const int gib = b * NN + it * 64;
  const unsigned short* Xtb = Xt + (size_t)b * 256 * 2048;
  const unsigned short* Xrb = Xr + (size_t)b * NN * 256;   // + row*256
  const int jgbase = g * 1024;                    // group's j range base

  int ksOff[4], vtOff[4], xsOff[4];
#pragma unroll
  for (int q = 0; q < 4; ++q) {
    int j = wg * 8 + q * 2 + (lane >> 5);
    int ck = (lane & 31) ^ (j & 7);               // K chunk swizzle
    ksOff[q] = j * 256 + ck * 8;
    int d = wg * 64 + q * 16 + (lane >> 2);
    int cv = (lane & 3) ^ ((d >> 1) & 3);         // V chunk swizzle
    vtOff[q] = d * 2048 + cv * 8;
    int xr = w * 8 + q * 2 + (lane >> 5);         // Xs row (0..63)
    xsOff[q] = (it * 64 + xr) * 256 + (((lane & 31) ^ (xr & 7)) * 8);
  }
  const int ldsOff = wg * 2048 + lane * 8;        // ushort units, per buffer

  bf16x8 qf[8];
  {
    const unsigned short* xrow = Xrb + (size_t)(it * 64 + wg * 16 + l15) * 256;
#pragma unroll
    for (int kc = 0; kc < 8; ++kc) {
      bf16x8 xb = *(const bf16x8*)(xrow + kc * 32 + quad * 8);
      const float* wp = w_map + kc * 32 + quad * 8;
      float4 w0 = *(const float4*)wp, w1 = *(const float4*)(wp + 4);
      float wv[8] = {w0.x, w0.y, w0.z, w0.w, w1.x, w1.y, w1.z, w1.w};
      bf16x8 q;
#pragma unroll
      for (int i = 0; i < 8; ++i)
        q[i] = (short)f2bf(bf2f((unsigned short)xb[i]) * wv[i]);
      qf[kc] = q;
    }
  }

  const f32x4 fz = {0.f, 0.f, 0.f, 0.f};
  f32x4 oacc[16];                                  // [d-tile]; col=query (swapped PV)
#pragma unroll
  for (int i = 0; i < 16; ++i) oacc[i] = fz;
  f32x4 oL = fz;

  bf16x8 onesFrag;
  {
    short o1 = (l15 == 0) ? (short)0x3F80 : (short)0;    // bf16 1.0, col 0
#pragma unroll
    for (int i = 0; i < 8; ++i) onesFrag[i] = o1;
  }

#pragma unroll
  for (int q = 0; q < 4; ++q)
    async_copy16(Xrb + (size_t)jgbase * 256 + ksOff[q], &Ks2[0][g][ldsOff + q * 512]);
#pragma unroll
  for (int q = 0; q < 4; ++q)
    async_copy16(Xtb + jgbase + vtOff[q], &Vt2[0][g][ldsOff + q * 512]);

  for (int jt = 0; jt < 32; ++jt) {
    const int cur = jt & 1;
    __syncthreads();            // buf[cur] landed; prev-iter buf[cur^1] reads done
    if (jt < 31) {              // prefetch jt+1, drains at NEXT barrier
      const int jb1 = jgbase + (jt + 1) * 32;
#pragma unroll
      for (int q = 0; q < 4; ++q)
        async_copy16(Xrb + (size_t)jb1 * 256 + ksOff[q], &Ks2[cur ^ 1][g][ldsOff + q * 512]);
#pragma unroll
      for (int q = 0; q < 4; ++q)
        async_copy16(Xtb + jb1 + vtOff[q], &Vt2[cur ^ 1][g][ldsOff + q * 512]);
    } else {                    // jt==31: stage this block's own x rows (Xs)
#pragma unroll
      for (int q = 0; q < 4; ++q)
        async_copy16(Xrb + (size_t)xsOff[q],
                     &Ks2[0][0][(w * 8 + q * 2) * 256 + lane * 8]);
    }
    // ---- S^T = K Q^T, two m-tiles (j = jm*16 + l15); exp -> Psw ----
#pragma unroll
    for (int jm = 0; jm < 2; ++jm) {
      const int j = jm * 16 + l15;
      f32x4 s = fz;
#pragma unroll
      for (int kc = 0; kc < 8; ++kc) {
        int ckk = kc * 4 + quad;
        bf16x8 kf = *(const bf16x8*)&Ks2[cur][g][j * 256 + ((ckk ^ (j & 7)) * 8)];
        s = MFMA16(kf, qf[kc], s);
      }
      ushort4 pk;
      pk.x = f2bf(__expf(s[0])); pk.y = f2bf(__expf(s[1]));
      pk.z = f2bf(__expf(s[2])); pk.w = f2bf(__expf(s[3]));
      *(ushort4*)&Psw[w][l15 * 40 + jm * 16 + quad * 4] = pk;   // ds_write_b64
    }
    // ---- PV (SWAPPED: A=Vt, B=P) -> C rows = d, cols = query ----
    bf16x8 af = *(const bf16x8*)&Psw[w][l15 * 40 + quad * 8];
#pragma unroll
    for (int nti = 0; nti < 16; ++nti) {
      const int d = nti * 16 + l15;
      bf16x8 vf = *(const bf16x8*)&Vt2[cur][g][d * 32 + ((quad ^ ((d >> 1) & 3)) * 8)];
      oacc[nti] = MFMA16(vf, af, oacc[nti]);
    }
    oL = MFMA16(af, onesFrag, oL);   // C rows = query, col 0
  }

  // ================= epilogue =================
  unsigned short* Xs  = &Ks2[0][0][0];             // [64][256] bf16 (32 KB)
  unsigned short* Agg = &Ks2[1][0][0];             // [64][256] bf16, chunk^(q&7)
  float* OB = (float*)&Vt2[0][0][0];               // [64 q][128 d] f32 (32 KB)

  // own L -> LDS; g1 parks d 0..127 (can touch Vt buf0: dead since barrier jt31)
  if (l15 == 0) {
#pragma unroll
    for (int r = 0; r < 4; ++r) LbG[g][wg * 16 + quad * 4 + r] = oL[r];
  }
  if (g == 1) {
    const int q = wg * 16 + l15;
#pragma unroll
    for (int nti = 0; nti < 8; ++nti) {
      int dd = nti * 16 + quad * 4;                // 0..124
      *(f32x4*)&OB[q * 128 + (dd ^ ((q & 7) * 4))] = oacc[nti];
    }
  }
  __syncthreads();                                 // E1: Xs DMA + parks + L visible

  // WC prefetch into VGPRs (no DMA in flight now -> no vmcnt hazard)
  bf16x8 wcf[2][16];
#pragma unroll
  for (int nt = 0; nt < 2; ++nt)
#pragma unroll
    for (int kc = 0; kc < 16; ++kc)
      wcf[nt][kc] = *(const bf16x8*)(WC + (size_t)(w * 32 + nt * 16 + l15) * 512 +
                                     kc * 32 + quad * 8);

  if (g == 0) {                                    // combine low d-half
    const int q = wg * 16 + l15;
#pragma unroll
    for (int nti = 0; nti < 8; ++nti) {
      int dd = nti * 16 + quad * 4;
      f32x4 p = *(const f32x4*)&OB[q * 128 + (dd ^ ((q & 7) * 4))];
#pragma unroll
      for (int r = 0; r < 4; ++r) oacc[nti][r] += p[r];
    }
  }
  __syncthreads();                                 // E2: low half consumed
  if (g == 1) {                                    // park high d-half
    const int q = wg * 16 + l15;
#pragma unroll
    for (int nti = 8; nti < 16; ++nti) {
      int dd = (nti - 8) * 16 + quad * 4;
      *(f32x4*)&OB[q * 128 + (dd ^ ((q & 7) * 4))] = oacc[nti];
    }
  }
  __syncthreads();                                 // E3: high parks visible
  if (g == 0) {
    const int q = wg * 16 + l15;
#pragma unroll
    for (int nti = 8; nti < 16; ++nti) {
      int dd = (nti - 8) * 16 + quad * 4;
      f32x4 p = *(const f32x4*)&OB[q * 128 + (dd ^ ((q & 7) * 4))];
#pragma unroll
      for (int r = 0; r < 4; ++r) oacc[nti][r] += p[r];
    }
    // normalize by total L and write Agg (b64 per d-block, chunk^(q&7))
    float li = 1.0f / (LbG[0][q] + LbG[1][q]);
#pragma unroll
    for (int nti = 0; nti < 16; ++nti) {
      ushort4 pk;
      pk.x = f2bf(oacc[nti][0] * li); pk.y = f2bf(oacc[nti][1] * li);
      pk.z = f2bf(oacc[nti][2] * li); pk.w = f2bf(oacc[nti][3] * li);
      int chunk = nti * 2 + (quad >> 1);           // d-chunk of 8
      *(ushort4*)&Agg[q * 256 + ((chunk ^ (q & 7)) * 8) + (quad & 1) * 4] = pk;
    }
  }
  __syncthreads();                                 // E4: Agg ready

  // ---- fused linear as out^T: A=WC (regs), B=Agg/Xs (LDS) ----
  f32x4 eacc[2][4];                                // [nt][rt]; rows=ch, cols=query
#pragma unroll
  for (int i = 0; i < 2; ++i)
#pragma unroll
    for (int j = 0; j < 4; ++j) eacc[i][j] = fz;

#pragma unroll
  for (int kc = 0; kc < 16; ++kc) {
    bf16x8 bfr[4];
#pragma unroll
    for (int rt = 0; rt < 4; ++rt) {
      const int row = rt * 16 + l15;
      if (kc < 8)
        bfr[rt] = *(const bf16x8*)&Agg[row * 256 + (((kc * 4 + quad) ^ (row & 7)) * 8)];
      else
        bfr[rt] = *(const bf16x8*)&Xs[row * 256 + ((((kc - 8) * 4 + quad) ^ (row & 7)) * 8)];
    }
#pragma unroll
    for (int nt = 0; nt < 2; ++nt)
#pragma unroll
      for (int rt = 0; rt < 4; ++rt)
        eacc[nt][rt] = MFMA16(wcf[nt][kc], bfr[rt], eacc[nt][rt]);
  }

  // ---- BN partial stats: channel = w*32 + nt*16 + quad*4 + r ----
#pragma unroll
  for (int nt = 0; nt < 2; ++nt)
#pragma unroll
    for (int r = 0; r < 4; ++r) {
      float a = 0.f, b2 = 0.f;
#pragma unroll
      for (int rt = 0; rt < 4; ++rt) {
        float v = eacc[nt][rt][r];
        a += v; b2 += v * v;
      }
      a += __shfl_xor(a, 1); a += __shfl_xor(a, 2);
      a += __shfl_xor(a, 4); a += __shfl_xor(a, 8);
      b2 += __shfl_xor(b2, 1); b2 += __shfl_xor(b2, 2);
      b2 += __shfl_xor(b2, 4); b2 += __shfl_xor(b2, 8);
      if (l15 == 0) {
        int ch = w * 32 + nt * 16 + quad * 4 + r;
        atomicAdd(&sums[ch], a);
        atomicAdd(&sums[256 + ch], b2);
      }
    }

  // ---- store pre-BN out: float4 per (nt, rt) ----
#pragma unroll
  for (int nt = 0; nt < 2; ++nt)
#pragma unroll
    for (int rt = 0; rt < 4; ++rt) {
      float4 v = {eacc[nt][rt][0], eacc[nt][rt][1], eacc[nt][rt][2], eacc[nt][rt][3]};
      *(float4*)&out[(size_t)(gib + rt * 16 + l15) * 256 + w * 32 + nt * 16 + quad * 4] = v;
    }
}

// ---------------------------------------------------------------------------
// k4: BatchNorm (biased var) + SELU, in place on d_out. Per-channel
// scale/shift computed once per block in LDS.
// ---------------------------------------------------------------------------
__global__ __launch_bounds__(256) void k4_bn_selu(float* __restrict__ out,
                                                  const float* __restrict__ sums,
                                                  const float* __restrict__ gamma,
                                                  const float* __restrict__ beta) {
  __shared__ float sc[256], sh[256];
  const int t = threadIdx.x;
  {
    const float inv_m = 1.0f / 16384.0f;
    float mean = sums[t] * inv_m;
    float var = sums[256 + t] * inv_m - mean * mean;
    float s = rsqrtf(var + BN_EPS) * gamma[t];
    sc[t] = s;
    sh[t] = beta[t] - mean * s;
  }
  __syncthreads();
  int f = (blockIdx.x * 256 + t) * 8;
  int c = f & 255;
  float4 v0 = *(const float4*)(out + f);
  float4 v1 = *(const float4*)(out + f + 4);
  float vv[8] = {v0.x, v0.y, v0.z, v0.w, v1.x, v1.y, v1.z, v1.w};
#pragma unroll
  for (int k = 0; k < 8; ++k) {
    int ch = c + k;
    float y = vv[k] * sc[ch] + sh[ch];
    float yc = fminf(fmaxf(y, -10.f), 10.f);
    float r = (y > 0.f) ? y : (SELU_ALPHA * (expf(yc) - 1.0f));
    vv[k] = SELU_SCALE * r;
  }
  float4 o0 = {vv[0], vv[1], vv[2], vv[3]};
  float4 o1 = {vv[4], vv[5], vv[6], vv[7]};
  *(float4*)(out + f) = o0;
  *(float4*)(out + f + 4) = o1;
}

// ---------------------------------------------------------------------------
extern "C" void kernel_launch(void* const* d_in, const int* in_sizes, int n_in,
                              void* d_out, int out_size, void* d_ws, size_t ws_size,
                              hipStream_t stream) {
  const float* x     = (const float*)d_in[0];
  const float* w_map = (const float*)d_in[1];
  const float* w_att = (const float*)d_in[2];
  const float* w_res = (const float*)d_in[3];
  const float* gamma = (const float*)d_in[4];
  const float* beta  = (const float*)d_in[5];
  float* out = (float*)d_out;

  // ws layout (~16.6 MB): Xr 8MB | Xt 8MB | WC 256KB | sums 2KB
  unsigned short* Xr = (unsigned short*)d_ws;
  unsigned short* Xt = Xr + (size_t)ROWS * 256;
  unsigned short* WC = Xt + (size_t)NB * 256 * 2048;
  float* sums = (float*)(WC + 256 * 512);

  k0_prep<<<576, 256, 0, stream>>>(x, w_att, w_res, Xr, Xt, WC, sums);
  k1_attn<<<256, 512, 0, stream>>>(w_map, Xr, Xt, WC, out, sums);
  k4_bn_selu<<<2048, 256, 0, stream>>>(out, sums, gamma, beta);
}